// Round 1
// 259.526 us; speedup vs baseline: 1.0910x; 1.0910x over previous
//
#include <hip/hip_runtime.h>

#define BB 512
#define TT 512
#define KK 64

typedef float v2f __attribute__((ext_vector_type(2)));

__device__ __forceinline__ float frl(float v, int lane) {
    return __int_as_float(__builtin_amdgcn_readlane(__float_as_int(v), lane));
}
// 3-input max in one VOP3 (clang won't fuse fmaxf chains without nnan)
__device__ __forceinline__ float fmax3(float a, float b, float c) {
    float d;
    asm("v_max3_f32 %0, %1, %2, %3" : "=v"(d) : "v"(a), "v"(b), "v"(c));
    return d;
}

// One UNCONDITIONAL Viterbi step via LDS broadcast. Stores the pre-unary max M
// (not alpha): alpha_t = PT + M_t is reconstructible bit-exactly, which lets the
// backtrace do equality-matching and lets us drop the freeze select entirely.
// DS ops are in-order within a wave -> clobber, no barrier.
#define FSTEP(PT) do {                                                          \
    la[lane] = alpha;                                                           \
    asm volatile("" ::: "memory");                                              \
    float acc0, acc1, acc2, acc3;                                               \
    {                                                                           \
        float4 a4 = ((float4*)la)[0];                                           \
        v2f lo; lo.x = a4.x; lo.y = a4.y; v2f cl = lo + tcl[0];                 \
        v2f hi; hi.x = a4.z; hi.y = a4.w; v2f ch = hi + tch[0];                 \
        acc0 = fmaxf(cl.x, cl.y); acc1 = fmaxf(ch.x, ch.y);                     \
        a4 = ((float4*)la)[1];                                                  \
        lo.x = a4.x; lo.y = a4.y; cl = lo + tcl[1];                             \
        hi.x = a4.z; hi.y = a4.w; ch = hi + tch[1];                             \
        acc2 = fmaxf(cl.x, cl.y); acc3 = fmaxf(ch.x, ch.y);                     \
    }                                                                           \
    _Pragma("unroll")                                                           \
    for (int c = 2; c < 16; c += 2) {                                           \
        float4 a4 = ((float4*)la)[c];                                           \
        v2f lo; lo.x = a4.x; lo.y = a4.y; v2f cl = lo + tcl[c];                 \
        v2f hi; hi.x = a4.z; hi.y = a4.w; v2f ch = hi + tch[c];                 \
        acc0 = fmax3(acc0, cl.x, cl.y); acc1 = fmax3(acc1, ch.x, ch.y);         \
        a4 = ((float4*)la)[c + 1];                                              \
        lo.x = a4.x; lo.y = a4.y; cl = lo + tcl[c + 1];                         \
        hi.x = a4.z; hi.y = a4.w; ch = hi + tch[c + 1];                         \
        acc2 = fmax3(acc2, cl.x, cl.y); acc3 = fmax3(acc3, ch.x, ch.y);         \
    }                                                                           \
    float M = fmaxf(fmax3(acc0, acc1, acc2), acc3);                             \
    *hp = M; hp += KK;                                                          \
    alpha = (PT) + M;                                                           \
} while (0)

// ---------------------------------------------------------------------------
// Fused: unconditional max-only forward (M-history to ws) -> late seq_len
// count (L3-warm) -> equality-match backtrace. One wave per batch, 1 dispatch.
// ---------------------------------------------------------------------------
__global__ __launch_bounds__(64, 1) void crf_fused(const float* __restrict__ pot,
                                                   const float* __restrict__ trans,
                                                   float* __restrict__ alphaH,
                                                   int* __restrict__ out) {
    __shared__ float tT[KK][KK + 1];   // tT[j][i] = trans[i][j] (backtrace)
    __shared__ float la[KK];           // alpha broadcast buffer (uniform reads)

    const int b = blockIdx.x;
    const int lane = threadIdx.x;
    const float* pb = pot + (size_t)b * TT * KK;
    float* hb = alphaH + (size_t)b * TT * KK;
    int* ob = out + b * TT;

    // ---- stage transposed trans for backtrace (same wave: no barrier) ----
    #pragma unroll 8
    for (int r = 0; r < KK; ++r) tT[lane][r] = trans[r * KK + lane];

    // ---- trans column 'lane' as v2f pairs; pin vs remat (proven R6) ----
    v2f tcl[16], tch[16];   // tcl[c] = rows 4c,4c+1; tch[c] = rows 4c+2,4c+3
    #pragma unroll
    for (int c = 0; c < 16; ++c) {
        v2f l2, h2;
        l2.x = trans[(4 * c + 0) * KK + lane]; l2.y = trans[(4 * c + 1) * KK + lane];
        h2.x = trans[(4 * c + 2) * KK + lane]; h2.y = trans[(4 * c + 3) * KK + lane];
        tcl[c] = l2; tch[c] = h2;
    }
    #pragma unroll
    for (int c = 0; c < 16; ++c) {
        asm volatile("" : "+v"(tcl[c]));
        asm volatile("" : "+v"(tch[c]));
    }

    // ------------------------------ forward ------------------------------
    // Unconditional (no freeze): frozen-state alpha is reconstructed later
    // from Mh + pot (bit-exact, same add). Row 0 of history := 0 so that
    // alpha_0 = pot_0 + Mh_0 holds uniformly for the backtrace.
    float alpha = pb[lane];
    hb[lane] = 0.0f;
    float* hp = hb + KK + lane;

    float pf[4] = { pb[1 * KK + lane], pb[2 * KK + lane], pb[3 * KK + lane], pb[4 * KK + lane] };
    const float* lp = pb + 5 * KK + lane;

    #pragma unroll 1
    for (int c = 0; c < 126; ++c) {          // t = 1..504
        #pragma unroll
        for (int u = 0; u < 4; ++u) {
            FSTEP(pf[u]);
            pf[u] = *lp; lp += KK;
        }
    }
    float e0 = pb[509 * KK + lane], e1 = pb[510 * KK + lane], e2 = pb[511 * KK + lane];
    FSTEP(pf[0]); FSTEP(pf[1]); FSTEP(pf[2]); FSTEP(pf[3]);
    FSTEP(e0);    FSTEP(e1);    FSTEP(e2);   // t = 505..511

    // ---- seq_len: AFTER forward (pb is L3-warm now; off the cold path) ----
    int cnt = 0;
    {
        const float4* p4 = (const float4*)pb;
        #pragma unroll 4
        for (int r = 0; r < 128; ++r) {
            float4 v = p4[lane + 64 * r];
            cnt += (v.x != 0.f) + (v.y != 0.f) + (v.z != 0.f) + (v.w != 0.f);
        }
        #pragma unroll
        for (int off = 32; off > 0; off >>= 1) cnt += __shfl_xor(cnt, off, 64);
    }
    const int seqlen = cnt >> 6;   // trunc(mean) — fp32-exact per R1

    asm volatile("s_waitcnt vmcnt(0)" ::: "memory");   // M-history visible to our loads

    // ---- final alpha: live register if no freeze, else exact reconstruct ----
    float afin = alpha;
    if (seqlen < TT) {
        if (seqlen <= 1) afin = pb[lane];                                   // alpha_0
        else afin = pb[(seqlen - 1) * KK + lane] + hb[(seqlen - 1) * KK + lane]; // pot + Mh (fwd order)
    }

    // ---- final argmax over alpha (first occurrence on ties) ----
    float v = afin; int idx = lane;
    #pragma unroll
    for (int off = 1; off < 64; off <<= 1) {
        float vo = __shfl_xor(v, off, 64);
        int io = __shfl_xor(idx, off, 64);
        bool take = (vo > v) || (vo == v && io < idx);
        v = take ? vo : v;
        idx = take ? io : idx;
    }
    int cur = idx;          // uniform
    int slot = cur;         // lane 63 slot survives as tag at t=511

    // ---- backtrace: EQUALITY MATCH (bit-exact), no DPP umax chain ----
    // bp_t(cur) = first i with (pot[t-1][i] + Mh[t-1][i]) + T[i][cur] == Mh[t][cur].
    // All three adds replay forward's exact IEEE ops, so a match always exists
    // and first-match == first-argmax (jnp.argmax tie semantics).
    float mrow = hb[511 * KK + lane];   // Mh[t] row carried down the walk
    float m0 = hb[510 * KK + lane], m1 = hb[509 * KK + lane], m2 = hb[508 * KK + lane],
          m3 = hb[507 * KK + lane], m4 = hb[506 * KK + lane], m5 = hb[505 * KK + lane],
          m6 = hb[504 * KK + lane], m7 = hb[503 * KK + lane];
    float p0 = pb[510 * KK + lane], p1 = pb[509 * KK + lane], p2 = pb[508 * KK + lane],
          p3 = pb[507 * KK + lane], p4 = pb[506 * KK + lane], p5 = pb[505 * KK + lane],
          p6 = pb[504 * KK + lane], p7 = pb[503 * KK + lane];

    auto bt_step = [&](int tt, float mlo, float plo) {
        if (tt < seqlen) {   // uniform
            float target = frl(mrow, cur);                 // Mh[tt][cur]
            float cand = (plo + mlo) + tT[cur][lane];      // alpha_{tt-1}[lane] + T[lane][cur]
            unsigned long long mk = __ballot(cand == target);
            if (mk) cur = (int)__builtin_ctzll(mk);        // first i == first argmax
        }
        mrow = mlo;
        const int tm = tt - 1;
        slot = ((tm & 63) == lane) ? cur : slot;
        if ((tm & 63) == 0) ob[tm + lane] = slot;
    };

    int T0 = 511;
    #pragma unroll 1
    for (int c = 0; c < 63; ++c) {
        bt_step(T0 - 0, m0, p0); { int pi = T0 - 9;  pi = pi < 0 ? 0 : pi; m0 = hb[pi * KK + lane]; p0 = pb[pi * KK + lane]; }
        bt_step(T0 - 1, m1, p1); { int pi = T0 - 10; pi = pi < 0 ? 0 : pi; m1 = hb[pi * KK + lane]; p1 = pb[pi * KK + lane]; }
        bt_step(T0 - 2, m2, p2); { int pi = T0 - 11; pi = pi < 0 ? 0 : pi; m2 = hb[pi * KK + lane]; p2 = pb[pi * KK + lane]; }
        bt_step(T0 - 3, m3, p3); { int pi = T0 - 12; pi = pi < 0 ? 0 : pi; m3 = hb[pi * KK + lane]; p3 = pb[pi * KK + lane]; }
        bt_step(T0 - 4, m4, p4); { int pi = T0 - 13; pi = pi < 0 ? 0 : pi; m4 = hb[pi * KK + lane]; p4 = pb[pi * KK + lane]; }
        bt_step(T0 - 5, m5, p5); { int pi = T0 - 14; pi = pi < 0 ? 0 : pi; m5 = hb[pi * KK + lane]; p5 = pb[pi * KK + lane]; }
        bt_step(T0 - 6, m6, p6); { int pi = T0 - 15; pi = pi < 0 ? 0 : pi; m6 = hb[pi * KK + lane]; p6 = pb[pi * KK + lane]; }
        bt_step(T0 - 7, m7, p7); { int pi = T0 - 16; pi = pi < 0 ? 0 : pi; m7 = hb[pi * KK + lane]; p7 = pb[pi * KK + lane]; }
        T0 -= 8;
    }
    bt_step(7, m0, p0); bt_step(6, m1, p1); bt_step(5, m2, p2); bt_step(4, m3, p3);
    bt_step(3, m4, p4); bt_step(2, m5, p5); bt_step(1, m6, p6);
}

// ---------------------------------------------------------------------------
// Fallback path (proven R1 kernels) -- only if ws can't hold the history.
// ---------------------------------------------------------------------------
__global__ __launch_bounds__(256) void seqlen_kernel(const float* __restrict__ inp,
                                                     int* __restrict__ seq_lens) {
    int b = blockIdx.x;
    int tid = threadIdx.x;
    const float4* p4 = (const float4*)(inp + (size_t)b * TT * KK);
    const int n4 = TT * KK / 4;
    int cnt = 0;
    for (int idx = tid; idx < n4; idx += 256) {
        float4 v = p4[idx];
        cnt += (v.x != 0.0f) + (v.y != 0.0f) + (v.z != 0.0f) + (v.w != 0.0f);
    }
    #pragma unroll
    for (int off = 32; off > 0; off >>= 1) cnt += __shfl_down(cnt, off, 64);
    __shared__ int wsum[4];
    if ((tid & 63) == 0) wsum[tid >> 6] = cnt;
    __syncthreads();
    if (tid == 0) seq_lens[b] = (wsum[0] + wsum[1] + wsum[2] + wsum[3]) >> 6;
}

__global__ __launch_bounds__(64) void viterbi_fallback(const float* __restrict__ pot,
                                                       const float* __restrict__ trans,
                                                       const int* __restrict__ seq_lens,
                                                       int* __restrict__ out) {
    __shared__ unsigned char bp[TT][KK];
    const int b = blockIdx.x;
    const int j = threadIdx.x;

    float tc[KK];
    #pragma unroll
    for (int i = 0; i < KK; ++i) tc[i] = trans[i * KK + j];

    const float* pb = pot + (size_t)b * TT * KK;
    float alpha = pb[j];
    const int seqlen = seq_lens[b];

    for (int t = 1; t < TT; ++t) {
        float ptj = pb[t * KK + j];
        float m[4]; int am[4];
        #pragma unroll
        for (int c = 0; c < 4; ++c) {
            const int i = c * 16;
            float ai = frl(alpha, i);
            m[c] = ai + tc[i];
            am[c] = i;
        }
        #pragma unroll
        for (int q = 1; q < 16; ++q) {
            #pragma unroll
            for (int c = 0; c < 4; ++c) {
                const int i = c * 16 + q;
                float ai = frl(alpha, i);
                float s = ai + tc[i];
                bool g = s > m[c];
                m[c] = g ? s : m[c];
                am[c] = g ? i : am[c];
            }
        }
        float M = m[0]; int BI = am[0];
        #pragma unroll
        for (int c = 1; c < 4; ++c) {
            bool g = m[c] > M;
            M = g ? m[c] : M;
            BI = g ? am[c] : BI;
        }
        const bool valid = (t < seqlen);
        alpha = valid ? (ptj + M) : alpha;
        bp[t][j] = (unsigned char)(valid ? BI : j);
    }

    float v = alpha; int idx = j;
    #pragma unroll
    for (int off = 1; off < 64; off <<= 1) {
        float vo = __shfl_xor(v, off, 64);
        int io = __shfl_xor(idx, off, 64);
        bool take = (vo > v) || (vo == v && io < idx);
        v = take ? vo : v;
        idx = take ? io : idx;
    }
    __syncthreads();
    if (j == 0) {
        int* ob = out + b * TT;
        int cur = idx;
        ob[TT - 1] = cur;
        for (int p = TT - 2; p >= 0; --p) {
            cur = bp[p + 1][cur];
            ob[p] = cur;
        }
    }
}

extern "C" void kernel_launch(void* const* d_in, const int* in_sizes, int n_in,
                              void* d_out, int out_size, void* d_ws, size_t ws_size,
                              hipStream_t stream) {
    const float* inp = (const float*)d_in[0];     // [B, T, K] fp32
    const float* trans = (const float*)d_in[1];   // [K, K] fp32
    int* out = (int*)d_out;                       // [B, T] int32

    const size_t histBytes = (size_t)BB * TT * KK * sizeof(float);  // 64 MB
    if (ws_size >= histBytes) {
        float* alphaH = (float*)d_ws;
        crf_fused<<<BB, 64, 0, stream>>>(inp, trans, alphaH, out);
    } else {
        int* seq = (int*)d_ws;
        seqlen_kernel<<<BB, 256, 0, stream>>>(inp, seq);
        viterbi_fallback<<<BB, KK, 0, stream>>>(inp, trans, seq, out);
    }
}